// Round 10
// baseline (141.450 us; speedup 1.0000x reference)
//
#include <hip/hip_runtime.h>
#include <hip/hip_bf16.h>

#define Bn    8
#define Cn    64
#define Hn    128
#define Wn    128
#define KK    9
#define OffC  18
#define NG    4
#define Cg    16
#define HW    (Hn*Wn)

#define OFFS_ELEMS (Bn*OffC*HW)
#define WAO_ELEMS  (KK*4*64*8)      // offset-conv A-fragments (bf16)
#define WAD_ELEMS  (NG*KK*64*8)     // deform A-fragments (bf16)

// deform tile geometry: 4 output rows, halo 2 up / 2 down
#define ROWS  4
#define TR    8
#define NW    8
#define TSTR  132

typedef __attribute__((ext_vector_type(8)))  short short8v;
typedef __attribute__((ext_vector_type(4)))  unsigned int uint4v;
typedef __attribute__((ext_vector_type(2)))  float f32x2;
typedef __attribute__((ext_vector_type(16))) float f32x16;

__device__ __forceinline__ unsigned int rne16(float f) {
    unsigned int u = __float_as_uint(f);
    return (u + 0x7FFFu + ((u >> 16) & 1u)) >> 16;   // bf16 RNE
}
// packed bf16 convert: one v_cvt_pk_bf16_f32 (HW-verified on gfx950)
__device__ __forceinline__ unsigned int pk2(float lo, float hi) {
    unsigned int w;
    asm("v_cvt_pk_bf16_f32 %0, %1, %2" : "=v"(w) : "v"(lo), "v"(hi));
    return w;
}

// ---------- Kernel 0: prep MFMA A-fragment tables (both convs) ----------
__global__ __launch_bounds__(256) void prep_w_kernel(
    const float* __restrict__ offw, const float* __restrict__ dw,
    unsigned short* __restrict__ wAo, unsigned short* __restrict__ wAd)
{
    const int tid = blockIdx.x * 256 + threadIdx.x;
    const int nth = gridDim.x * 256;
    for (int i = tid; i < WAO_ELEMS; i += nth) {
        const int e    = i & 7;
        const int lane = (i >> 3) & 63;
        const int q    = (i >> 9) & 3;
        const int t    = i >> 11;
        const int o    = lane & 31;
        const int c    = q * 16 + 8 * (lane >> 5) + e;
        const float v  = (o < OffC) ? offw[(o * Cn + c) * KK + t] : 0.f;
        wAo[i] = (unsigned short)rne16(v);
    }
    for (int i = tid; i < WAD_ELEMS; i += nth) {
        const int e    = i & 7;
        const int lane = (i >> 3) & 63;
        const int t    = (i >> 9) % KK;
        const int g    = i / (512 * KK);
        const int o    = lane & 31;
        const int c    = 8 * (lane >> 5) + e;
        const float v  = (o < Cg) ? dw[((g * Cg + o) * Cg + c) * KK + t] : 0.f;
        wAd[i] = (unsigned short)rne16(v);
    }
}

// ---------- Kernel 1: offset conv via MFMA, q-split x2 + LDS reduce ----------
// grid (Hn, Bn, 2), 256 thr (4 waves). Wave wv: chunk c = wv&1 (32 cols),
// q-half qh = wv>>1 (q in {2qh, 2qh+1}). qh=1 waves dump acc to LDS; qh=0 adds+stores.
__global__ __launch_bounds__(256, 6) void offset_conv_kernel(
    const float* __restrict__ x, const unsigned short* __restrict__ wAo,
    const float* __restrict__ bias, float* __restrict__ offs)
{
    __shared__ float red[2][64][17];   // stride 17: conflict-free
    const int tid  = threadIdx.x;
    const int wv   = tid >> 6;
    const int lane = tid & 63;
    const int p    = lane & 31;
    const int h    = lane >> 5;
    const int b    = blockIdx.y;
    const int r    = blockIdx.x;
    const int ck   = wv & 1;
    const int qh   = wv >> 1;
    const int col  = blockIdx.z * 64 + ck * 32 + p;

    const float* xb = x + (size_t)b * Cn * HW;

    f32x16 acc;
#pragma unroll
    for (int i = 0; i < 16; ++i) acc[i] = 0.f;

#pragma unroll 1
    for (int qq = 0; qq < 2; ++qq) {
        const int q = 2 * qh + qq;
        unsigned int win[4][3][3];
#pragma unroll
        for (int i = 0; i < 4; ++i) {
            const float* xc0 = xb + (size_t)(q * 16 + 8 * h + 2 * i) * HW;
            const float* xc1 = xc0 + HW;
#pragma unroll
            for (int ky = 0; ky < 3; ++ky) {
                const int  y   = r - 1 + ky;
                const bool yok = ((unsigned)y < (unsigned)Hn);
#pragma unroll
                for (int kx = 0; kx < 3; ++kx) {
                    const int  xx = col - 1 + kx;
                    const bool ok = yok && ((unsigned)xx < (unsigned)Wn);
                    const float f0 = ok ? xc0[y * Wn + xx] : 0.f;
                    const float f1 = ok ? xc1[y * Wn + xx] : 0.f;
                    win[i][ky][kx] = pk2(f0, f1);
                }
            }
        }
#pragma unroll
        for (int t = 0; t < KK; ++t) {
            uint4v bw;
            bw[0] = win[0][t / 3][t % 3];
            bw[1] = win[1][t / 3][t % 3];
            bw[2] = win[2][t / 3][t % 3];
            bw[3] = win[3][t / 3][t % 3];
            const short8v bfrag = __builtin_bit_cast(short8v, bw);
            const short8v afrag = *(const short8v*)(wAo + (size_t)(t * 4 + q) * 512 + lane * 8);
            acc = __builtin_amdgcn_mfma_f32_32x32x16_bf16(afrag, bfrag, acc, 0, 0, 0);
        }
    }

    if (qh == 1) {
#pragma unroll
        for (int i = 0; i < 16; ++i) red[ck][lane][i] = acc[i];
    }
    __syncthreads();
    if (qh == 0) {
        float* ob = offs + ((size_t)b * OffC * Hn + r) * Wn + col;
#pragma unroll
        for (int reg = 0; reg < 16; ++reg) {
            const int o = (reg & 3) + 8 * (reg >> 2) + 4 * h;
            if (o < OffC) ob[(size_t)o * HW] = acc[reg] + red[ck][lane][reg] + bias[o];
        }
    }
}

// ---------- Kernel 2: deform conv — LDS bf16 tile + packed bilerp + MFMA ----------
// grid (Hn/ROWS, Bn*NG), 512 thr (8 waves). Wave wv: row r0+(wv>>1),
// chunk pair jb = (wv&1)*2. lane: p=pixel, h=channel-half.
__global__ __launch_bounds__(512, 6) void deform_kernel(
    const float* __restrict__ skip, const float* __restrict__ offs,
    const unsigned short* __restrict__ wA, float* __restrict__ out)
{
    __shared__ unsigned int tile[NW * TR * TSTR];   // 33792 B -> 4 blocks/CU

    const int tid = threadIdx.x;
    const int g = blockIdx.y & 3;
    const int b = blockIdx.y >> 2;
    const int r0  = blockIdx.x * ROWS;
    const int ylo = max(0, r0 - 2);
    const int yhi = min(Hn - 1, r0 + ROWS + 1);

    const float* sg = skip + (size_t)(b * Cn + g * Cg) * HW;

    // stage skip window as bf16 channel-pairs: tile[(w*TR+ty)*TSTR + x]
    for (int i = tid; i < NW * TR * Wn; i += 512) {
        const int w  = i >> 10;          // TR*Wn = 1024
        const int re = i & 1023;
        const int ty = re >> 7;
        const int xx = re & 127;
        const int y  = ylo + ty;
        if (y <= yhi) {
            const float f0 = sg[(2 * w)     * HW + y * Wn + xx];
            const float f1 = sg[(2 * w + 1) * HW + y * Wn + xx];
            tile[(w * TR + ty) * TSTR + xx] = pk2(f0, f1);
        }
    }
    __syncthreads();

    const int wv   = tid >> 6;
    const int lane = tid & 63;
    const int p    = lane & 31;
    const int h    = lane >> 5;
    const int r    = r0 + (wv >> 1);
    const int jb   = (wv & 1) * 2;

    const unsigned short* wAg = wA + (size_t)g * (KK * 512) + lane * 8;
    const float* offb = offs + (size_t)b * OffC * HW + r * Wn;

    for (int jj = 0; jj < 2; ++jj) {
        const int col = (jb + jj) * 32 + p;
        f32x16 acc;
#pragma unroll
        for (int i = 0; i < 16; ++i) acc[i] = 0.f;

        const float* offp = offb + col;

#pragma unroll 2
        for (int t = 0; t < KK; ++t) {
            const int ky = t / 3, kx = t % 3;
            const float offy = offp[(2 * t) * HW];
            const float offx = offp[(2 * t + 1) * HW];
            const float pyf = (float)(r - 1 + ky) + offy;
            const float pxf = (float)(col - 1 + kx) + offx;
            const float y0f = floorf(pyf), x0f = floorf(pxf);
            const float wy = pyf - y0f, wx = pxf - x0f;
            const int y0 = (int)y0f, x0 = (int)x0f, y1 = y0 + 1, x1 = x0 + 1;
            const bool vy0 = ((unsigned)y0 < (unsigned)Hn), vy1 = ((unsigned)y1 < (unsigned)Hn);
            const bool vx0 = ((unsigned)x0 < (unsigned)Wn), vx1 = ((unsigned)x1 < (unsigned)Wn);
            const int y0c = min(max(y0, 0), Hn - 1), y1c = min(max(y1, 0), Hn - 1);
            const int x0c = min(max(x0, 0), Wn - 1), x1c = min(max(x1, 0), Wn - 1);
            const float m0 = (1.f - wy) * (1.f - wx) * ((vy0 && vx0) ? 1.f : 0.f);
            const float m1 = (1.f - wy) * wx         * ((vy0 && vx1) ? 1.f : 0.f);
            const float m2 = wy * (1.f - wx)         * ((vy1 && vx0) ? 1.f : 0.f);
            const float m3 = wy * wx                 * ((vy1 && vx1) ? 1.f : 0.f);
            const bool cond = (y0c >= ylo) && (y1c <= yhi);

            f32x2 sv[4];
            if (cond) {
                const int tr0 = y0c - ylo, tr1 = y1c - ylo;
#pragma unroll
                for (int wi = 0; wi < 4; ++wi) {
                    const unsigned int* tw = tile + ((4 * h + wi) * TR) * TSTR;
                    const unsigned int u00 = tw[tr0 * TSTR + x0c];
                    const unsigned int u01 = tw[tr0 * TSTR + x1c];
                    const unsigned int u10 = tw[tr1 * TSTR + x0c];
                    const unsigned int u11 = tw[tr1 * TSTR + x1c];
                    f32x2 c00, c01, c10, c11;
                    c00[0] = __uint_as_float(u00 << 16); c00[1] = __uint_as_float(u00 & 0xFFFF0000u);
                    c01[0] = __uint_as_float(u01 << 16); c01[1] = __uint_as_float(u01 & 0xFFFF0000u);
                    c10[0] = __uint_as_float(u10 << 16); c10[1] = __uint_as_float(u10 & 0xFFFF0000u);
                    c11[0] = __uint_as_float(u11 << 16); c11[1] = __uint_as_float(u11 & 0xFFFF0000u);
                    sv[wi] = c00 * m0 + c01 * m1 + c10 * m2 + c11 * m3;   // v_pk_fma_f32
                }
            } else {
                const int ia0 = y0c * Wn + x0c, ia1 = y0c * Wn + x1c;
                const int ia2 = y1c * Wn + x0c, ia3 = y1c * Wn + x1c;
#pragma unroll
                for (int wi = 0; wi < 4; ++wi) {
                    const float* sc0 = sg + (size_t)(8 * h + 2 * wi) * HW;
                    const float* sc1 = sc0 + HW;
                    sv[wi][0] = sc0[ia0] * m0 + sc0[ia1] * m1 + sc0[ia2] * m2 + sc0[ia3] * m3;
                    sv[wi][1] = sc1[ia0] * m0 + sc1[ia1] * m1 + sc1[ia2] * m2 + sc1[ia3] * m3;
                }
            }

            uint4v bw;
#pragma unroll
            for (int wi = 0; wi < 4; ++wi) bw[wi] = pk2(sv[wi][0], sv[wi][1]);
            const short8v bfrag = __builtin_bit_cast(short8v, bw);
            const short8v afrag = *(const short8v*)(wAg + t * 512);

            acc = __builtin_amdgcn_mfma_f32_32x32x16_bf16(afrag, bfrag, acc, 0, 0, 0);
        }

        float* ob = out + (size_t)(b * Cn + g * Cg) * HW + r * Wn + col;
#pragma unroll
        for (int reg = 0; reg < 8; ++reg) {
            const int o = (reg & 3) + 8 * (reg >> 2) + 4 * h;
            ob[o * HW] = acc[reg];
        }
    }
}

extern "C" void kernel_launch(void* const* d_in, const int* in_sizes, int n_in,
                              void* d_out, int out_size, void* d_ws, size_t ws_size,
                              hipStream_t stream) {
    const float* x        = (const float*)d_in[0];
    const float* skip     = (const float*)d_in[1];
    const float* offset_w = (const float*)d_in[2];
    const float* offset_b = (const float*)d_in[3];
    const float* deform_w = (const float*)d_in[4];
    float* out  = (float*)d_out;

    float* offs = (float*)d_ws;                                   // 9.44 MB
    unsigned short* wAo = (unsigned short*)(offs + OFFS_ELEMS);   // 36.9 KB
    unsigned short* wAd = wAo + WAO_ELEMS;                        // 36.9 KB

    hipLaunchKernelGGL(prep_w_kernel, dim3(8), dim3(256), 0, stream,
                       offset_w, deform_w, wAo, wAd);
    hipLaunchKernelGGL(offset_conv_kernel, dim3(Hn, Bn, 2), dim3(256), 0, stream,
                       x, wAo, offset_b, offs);
    hipLaunchKernelGGL(deform_kernel, dim3(Hn / ROWS, Bn * NG), dim3(512), 0, stream,
                       skip, offs, wAd, out);
}

// Round 11
// 83.961 us; speedup vs baseline: 1.6847x; 1.6847x over previous
//
#include <hip/hip_runtime.h>

#define Bn    8
#define Cn    64
#define Hn    128
#define Wn    128
#define KK    9
#define OffC  18
#define NG    4
#define Cg    16
#define HW    (Hn*Wn)

#define OFFS_ELEMS (Bn*OffC*HW)
#define WAO_ELEMS  (KK*4*64*8)      // offset-conv A-fragments (bf16)
#define WAD_ELEMS  (NG*KK*64*8)     // deform A-fragments (bf16)

// deform tile geometry: 4 output rows, halo 2 up / 2 down
#define ROWS  4
#define TR    8
#define NW    8
#define TSTR  132

typedef __attribute__((ext_vector_type(8)))  short short8v;
typedef __attribute__((ext_vector_type(4)))  unsigned int uint4v;
typedef __attribute__((ext_vector_type(2)))  float f32x2;
typedef __attribute__((ext_vector_type(16))) float f32x16;

__device__ __forceinline__ unsigned int rne16(float f) {
    unsigned int u = __float_as_uint(f);
    return (u + 0x7FFFu + ((u >> 16) & 1u)) >> 16;   // bf16 RNE
}
__device__ __forceinline__ unsigned int pack2(float lo, float hi) {
    const unsigned int a = rne16(lo);
    unsigned int b = __float_as_uint(hi);
    b = (b + 0x7FFFu + ((b >> 16) & 1u)) & 0xFFFF0000u;
    return b | a;
}
// packed bf16 convert: one v_cvt_pk_bf16_f32
__device__ __forceinline__ unsigned int pk2(float lo, float hi) {
    unsigned int w;
    asm("v_cvt_pk_bf16_f32 %0, %1, %2" : "=v"(w) : "v"(lo), "v"(hi));
    return w;
}

// ---------- Kernel 0: prep MFMA A-fragment tables (both convs) ----------
__global__ __launch_bounds__(256) void prep_w_kernel(
    const float* __restrict__ offw, const float* __restrict__ dw,
    unsigned short* __restrict__ wAo, unsigned short* __restrict__ wAd)
{
    const int tid = blockIdx.x * 256 + threadIdx.x;
    const int nth = gridDim.x * 256;
    for (int i = tid; i < WAO_ELEMS; i += nth) {
        const int e    = i & 7;
        const int lane = (i >> 3) & 63;
        const int q    = (i >> 9) & 3;
        const int t    = i >> 11;
        const int o    = lane & 31;
        const int c    = q * 16 + 8 * (lane >> 5) + e;
        const float v  = (o < OffC) ? offw[(o * Cn + c) * KK + t] : 0.f;
        wAo[i] = (unsigned short)rne16(v);
    }
    for (int i = tid; i < WAD_ELEMS; i += nth) {
        const int e    = i & 7;
        const int lane = (i >> 3) & 63;
        const int t    = (i >> 9) % KK;
        const int g    = i / (512 * KK);
        const int o    = lane & 31;
        const int c    = 8 * (lane >> 5) + e;
        const float v  = (o < Cg) ? dw[((g * Cg + o) * Cg + c) * KK + t] : 0.f;
        wAd[i] = (unsigned short)rne16(v);
    }
}

// ---------- Kernel 1: offset conv via MFMA, 1 chunk/wave (PROVEN ~22 us, round 9) ----------
__global__ __launch_bounds__(256, 4) void offset_conv_kernel(
    const float* __restrict__ x, const unsigned short* __restrict__ wAo,
    const float* __restrict__ bias, float* __restrict__ offs)
{
    const int tid  = threadIdx.x;
    const int wv   = tid >> 6;
    const int lane = tid & 63;
    const int p    = lane & 31;
    const int h    = lane >> 5;
    const int b    = blockIdx.y;
    const int r    = blockIdx.x;
    const int col  = wv * 32 + p;

    const float* xb = x + (size_t)b * Cn * HW;

    f32x16 acc;
#pragma unroll
    for (int i = 0; i < 16; ++i) acc[i] = 0.f;

#pragma unroll 1
    for (int q = 0; q < 4; ++q) {
        unsigned int win[4][3][3];
#pragma unroll
        for (int i = 0; i < 4; ++i) {
            const float* xc0 = xb + (size_t)(q * 16 + 8 * h + 2 * i) * HW;
            const float* xc1 = xc0 + HW;
#pragma unroll
            for (int ky = 0; ky < 3; ++ky) {
                const int  y   = r - 1 + ky;
                const bool yok = ((unsigned)y < (unsigned)Hn);
#pragma unroll
                for (int kx = 0; kx < 3; ++kx) {
                    const int  xx = col - 1 + kx;
                    const bool ok = yok && ((unsigned)xx < (unsigned)Wn);
                    const float f0 = ok ? xc0[y * Wn + xx] : 0.f;
                    const float f1 = ok ? xc1[y * Wn + xx] : 0.f;
                    win[i][ky][kx] = pack2(f0, f1);
                }
            }
        }
#pragma unroll
        for (int t = 0; t < KK; ++t) {
            uint4v bw;
            bw[0] = win[0][t / 3][t % 3];
            bw[1] = win[1][t / 3][t % 3];
            bw[2] = win[2][t / 3][t % 3];
            bw[3] = win[3][t / 3][t % 3];
            const short8v bfrag = __builtin_bit_cast(short8v, bw);
            const short8v afrag = *(const short8v*)(wAo + (size_t)(t * 4 + q) * 512 + lane * 8);
            acc = __builtin_amdgcn_mfma_f32_32x32x16_bf16(afrag, bfrag, acc, 0, 0, 0);
        }
    }

    float* ob = offs + ((size_t)b * OffC * Hn + r) * Wn + col;
#pragma unroll
    for (int reg = 0; reg < 16; ++reg) {
        const int o = (reg & 3) + 8 * (reg >> 2) + 4 * h;
        if (o < OffC) ob[(size_t)o * HW] = acc[reg] + bias[o];
    }
}

// ---------- Kernel 2: deform conv — small LDS tile (4 blocks/CU) + packed bilerp + MFMA ----------
// grid (Hn/ROWS, Bn*NG), 512 thr (8 waves). Wave wv: row r0+(wv>>1), chunk pair (wv&1)*2.
// __launch_bounds__(512,4): VGPR cap 128 — compiler picks its natural ~64-80, NO spill.
__global__ __launch_bounds__(512, 4) void deform_kernel(
    const float* __restrict__ skip, const float* __restrict__ offs,
    const unsigned short* __restrict__ wA, float* __restrict__ out)
{
    __shared__ unsigned int tile[NW * TR * TSTR];   // 33792 B -> 4 blocks/CU

    const int tid = threadIdx.x;
    const int g = blockIdx.y & 3;
    const int b = blockIdx.y >> 2;
    const int r0  = blockIdx.x * ROWS;
    const int ylo = max(0, r0 - 2);
    const int yhi = min(Hn - 1, r0 + ROWS + 1);

    const float* sg = skip + (size_t)(b * Cn + g * Cg) * HW;

    // stage skip window as bf16 channel-pairs: tile[(w*TR+ty)*TSTR + x]
    for (int i = tid; i < NW * TR * Wn; i += 512) {
        const int w  = i >> 10;          // TR*Wn = 1024
        const int re = i & 1023;
        const int ty = re >> 7;
        const int xx = re & 127;
        const int y  = ylo + ty;
        if (y <= yhi) {
            const float f0 = sg[(2 * w)     * HW + y * Wn + xx];
            const float f1 = sg[(2 * w + 1) * HW + y * Wn + xx];
            tile[(w * TR + ty) * TSTR + xx] = pk2(f0, f1);
        }
    }
    __syncthreads();

    const int wv   = tid >> 6;
    const int lane = tid & 63;
    const int p    = lane & 31;
    const int h    = lane >> 5;
    const int r    = r0 + (wv >> 1);
    const int jb   = (wv & 1) * 2;

    const unsigned short* wAg = wA + (size_t)g * (KK * 512) + lane * 8;
    const float* offb = offs + (size_t)b * OffC * HW + r * Wn;

    for (int jj = 0; jj < 2; ++jj) {
        const int col = (jb + jj) * 32 + p;
        f32x16 acc;
#pragma unroll
        for (int i = 0; i < 16; ++i) acc[i] = 0.f;

        const float* offp = offb + col;

#pragma unroll 2
        for (int t = 0; t < KK; ++t) {
            const int ky = t / 3, kx = t % 3;
            const float offy = offp[(2 * t) * HW];
            const float offx = offp[(2 * t + 1) * HW];
            const float pyf = (float)(r - 1 + ky) + offy;
            const float pxf = (float)(col - 1 + kx) + offx;
            const float y0f = floorf(pyf), x0f = floorf(pxf);
            const float wy = pyf - y0f, wx = pxf - x0f;
            const int y0 = (int)y0f, x0 = (int)x0f, y1 = y0 + 1, x1 = x0 + 1;
            const bool vy0 = ((unsigned)y0 < (unsigned)Hn), vy1 = ((unsigned)y1 < (unsigned)Hn);
            const bool vx0 = ((unsigned)x0 < (unsigned)Wn), vx1 = ((unsigned)x1 < (unsigned)Wn);
            const int y0c = min(max(y0, 0), Hn - 1), y1c = min(max(y1, 0), Hn - 1);
            const int x0c = min(max(x0, 0), Wn - 1), x1c = min(max(x1, 0), Wn - 1);
            const float m0 = (1.f - wy) * (1.f - wx) * ((vy0 && vx0) ? 1.f : 0.f);
            const float m1 = (1.f - wy) * wx         * ((vy0 && vx1) ? 1.f : 0.f);
            const float m2 = wy * (1.f - wx)         * ((vy1 && vx0) ? 1.f : 0.f);
            const float m3 = wy * wx                 * ((vy1 && vx1) ? 1.f : 0.f);
            const bool cond = (y0c >= ylo) && (y1c <= yhi);

            f32x2 sv[4];
            if (cond) {
                const int tr0 = y0c - ylo, tr1 = y1c - ylo;
#pragma unroll
                for (int wi = 0; wi < 4; ++wi) {
                    const unsigned int* tw = tile + ((4 * h + wi) * TR) * TSTR;
                    const unsigned int u00 = tw[tr0 * TSTR + x0c];
                    const unsigned int u01 = tw[tr0 * TSTR + x1c];
                    const unsigned int u10 = tw[tr1 * TSTR + x0c];
                    const unsigned int u11 = tw[tr1 * TSTR + x1c];
                    f32x2 c00, c01, c10, c11;
                    c00[0] = __uint_as_float(u00 << 16); c00[1] = __uint_as_float(u00 & 0xFFFF0000u);
                    c01[0] = __uint_as_float(u01 << 16); c01[1] = __uint_as_float(u01 & 0xFFFF0000u);
                    c10[0] = __uint_as_float(u10 << 16); c10[1] = __uint_as_float(u10 & 0xFFFF0000u);
                    c11[0] = __uint_as_float(u11 << 16); c11[1] = __uint_as_float(u11 & 0xFFFF0000u);
                    sv[wi] = c00 * m0 + c01 * m1 + c10 * m2 + c11 * m3;   // v_pk_fma_f32
                }
            } else {
                const int ia0 = y0c * Wn + x0c, ia1 = y0c * Wn + x1c;
                const int ia2 = y1c * Wn + x0c, ia3 = y1c * Wn + x1c;
#pragma unroll
                for (int wi = 0; wi < 4; ++wi) {
                    const float* sc0 = sg + (size_t)(8 * h + 2 * wi) * HW;
                    const float* sc1 = sc0 + HW;
                    sv[wi][0] = sc0[ia0] * m0 + sc0[ia1] * m1 + sc0[ia2] * m2 + sc0[ia3] * m3;
                    sv[wi][1] = sc1[ia0] * m0 + sc1[ia1] * m1 + sc1[ia2] * m2 + sc1[ia3] * m3;
                }
            }

            uint4v bw;
#pragma unroll
            for (int wi = 0; wi < 4; ++wi) bw[wi] = pk2(sv[wi][0], sv[wi][1]);
            const short8v bfrag = __builtin_bit_cast(short8v, bw);
            const short8v afrag = *(const short8v*)(wAg + t * 512);

            acc = __builtin_amdgcn_mfma_f32_32x32x16_bf16(afrag, bfrag, acc, 0, 0, 0);
        }

        float* ob = out + (size_t)(b * Cn + g * Cg) * HW + r * Wn + col;
#pragma unroll
        for (int reg = 0; reg < 8; ++reg) {
            const int o = (reg & 3) + 8 * (reg >> 2) + 4 * h;
            ob[o * HW] = acc[reg];
        }
    }
}

extern "C" void kernel_launch(void* const* d_in, const int* in_sizes, int n_in,
                              void* d_out, int out_size, void* d_ws, size_t ws_size,
                              hipStream_t stream) {
    const float* x        = (const float*)d_in[0];
    const float* skip     = (const float*)d_in[1];
    const float* offset_w = (const float*)d_in[2];
    const float* offset_b = (const float*)d_in[3];
    const float* deform_w = (const float*)d_in[4];
    float* out  = (float*)d_out;

    float* offs = (float*)d_ws;                                   // 9.44 MB
    unsigned short* wAo = (unsigned short*)(offs + OFFS_ELEMS);   // 36.9 KB
    unsigned short* wAd = wAo + WAO_ELEMS;                        // 36.9 KB

    hipLaunchKernelGGL(prep_w_kernel, dim3(8), dim3(256), 0, stream,
                       offset_w, deform_w, wAo, wAd);
    hipLaunchKernelGGL(offset_conv_kernel, dim3(Hn, Bn), dim3(256), 0, stream,
                       x, wAo, offset_b, offs);
    hipLaunchKernelGGL(deform_kernel, dim3(Hn / ROWS, Bn * NG), dim3(512), 0, stream,
                       skip, offs, wAd, out);
}